// Round 6
// baseline (1074.068 us; speedup 1.0000x reference)
//
#include <hip/hip_runtime.h>
#include <hip/hip_bf16.h>
#include <math.h>
#include <stdint.h>

// ---------------------------------------------------------------------------
// Bidirectional Mamba block + FFN.
// Big GEMMs: split-fp32 (bf16 hi/lo x3) MFMA, m97-style 128x128 tile, BK=32,
//   double-buffered LDS staged via global_load_lds width-16.
// Small GEMMs (proj N=80, delta K=64), conv, scan, LN: fp32 VALU.
// Backward direction via per-lane global-source row index XOR 2047 (L=2048).
// ---------------------------------------------------------------------------

#define NTOK   4096
#define DM     1024
#define LSEQ   2048
#define NSTATE 8
#define NCHUNK 64
#define LCHUNK 32

typedef __attribute__((ext_vector_type(8))) short short8;
typedef __attribute__((ext_vector_type(4))) float floatx4;

__device__ __forceinline__ float softplus_f(float v) {
    return (v > 20.f) ? v : log1pf(__expf(v));
}
__device__ __forceinline__ float silu_f(float v) {
    return v / (1.f + __expf(-v));
}

// bf16 helpers (manual RNE)
__device__ __forceinline__ unsigned short f2bf(float x) {
    union { float f; unsigned int u; } a; a.f = x;
    const unsigned int r = a.u + 0x7fffu + ((a.u >> 16) & 1u);
    return (unsigned short)(r >> 16);
}
__device__ __forceinline__ float bf2f(unsigned short h) {
    union { unsigned int u; float f; } a; a.u = ((unsigned int)h) << 16;
    return a.f;
}
__device__ __forceinline__ void split2(float x, unsigned short& h, unsigned short& l) {
    h = f2bf(x);
    l = f2bf(x - bf2f(h));
}

// async global -> LDS, 16 bytes per lane. LDS dest is linear in lane with
// stride 16 B (HW requirement: wave-uniform base + lane*size, m104/m108).
// inttoptr is used deliberately: reinterpret_cast across address spaces is
// ill-formed in clang, but int->AS-ptr always compiles, and gfx9-lineage LDS
// aperture has zero low-32 bits so the truncation yields the LDS offset.
__device__ __forceinline__ void gload16(const void* g, void* l) {
#if __has_builtin(__builtin_amdgcn_global_load_lds)
    __builtin_amdgcn_global_load_lds(
        reinterpret_cast<const __attribute__((address_space(1))) unsigned int*>(
            reinterpret_cast<uintptr_t>(g)),
        reinterpret_cast<__attribute__((address_space(3))) unsigned int*>(
            reinterpret_cast<uintptr_t>(l)),
        16, 0, 0);
#else
    *reinterpret_cast<uint4*>(l) = *reinterpret_cast<const uint4*>(g);
#endif
}

// ---------------------------------------------------------------------------
// Transpose x (B, D, L) -> xt (B, L, D) fp32 + hi/lo bf16
// ---------------------------------------------------------------------------
__global__ __launch_bounds__(256) void transpose_k(const float* __restrict__ x,
                                                   float* __restrict__ xt,
                                                   unsigned short* __restrict__ xth,
                                                   unsigned short* __restrict__ xtl) {
    __shared__ float tile[32][33];
    const int b  = blockIdx.z;
    const int l0 = blockIdx.x * 32;
    const int d0 = blockIdx.y * 32;
    const int tx = threadIdx.x, ty = threadIdx.y;   // (32, 8)
    const float* src = x + (size_t)b * DM * LSEQ;
    #pragma unroll
    for (int i = 0; i < 4; i++)
        tile[ty + i * 8][tx] = src[(size_t)(d0 + ty + i * 8) * LSEQ + l0 + tx];
    __syncthreads();
    const size_t base = (size_t)b * LSEQ * DM;
    #pragma unroll
    for (int i = 0; i < 4; i++) {
        const float v = tile[tx][ty + i * 8];
        const size_t idx = base + (size_t)(l0 + ty + i * 8) * DM + d0 + tx;
        xt[idx] = v;
        unsigned short h, l;
        split2(v, h, l);
        xth[idx] = h;
        xtl[idx] = l;
    }
}

// ---------------------------------------------------------------------------
// Weight split: fp32 -> hi/lo bf16 (n4 = n/4 float4 groups)
// ---------------------------------------------------------------------------
__global__ __launch_bounds__(256) void split_k(const float* __restrict__ w,
                                               unsigned short* __restrict__ hi,
                                               unsigned short* __restrict__ lo,
                                               int n4) {
    const int i = blockIdx.x * 256 + threadIdx.x;
    if (i >= n4) return;
    const float4 v = ((const float4*)w)[i];
    ushort4 h, l;
    split2(v.x, h.x, l.x);
    split2(v.y, h.y, l.y);
    split2(v.z, h.z, l.z);
    split2(v.w, h.w, l.w);
    ((ushort4*)hi)[i] = h;
    ((ushort4*)lo)[i] = l;
}

// ---------------------------------------------------------------------------
// MFMA split-fp32 GEMM: C[M,N] = A[M,K] @ B[N,K]^T via bf16 hi/lo, 3 MFMA terms
// (hi*hi + hi*lo + lo*hi; lo*lo ~2^-32, dropped).
// BM=BN=128, BK=32, 256 threads = 4 waves, each wave owns a 64x64 sub-tile
// (wr,wc), computing 4x4 frags of 16x16x32. Note: A/B frags use the same
// row-major [row][k8] LDS read; any k-permutation cancels between A and B,
// so only the (verified) C/D mapping is layout-critical.
// AMODE: 1 = A row read reversed (row ^ 2047)
// EPI: 0 plain fp32 store
//      1 relu(acc+bias) -> bf16 hi/lo stores (Ch/Cl)     [FFN1]
//      2 acc+bias+res -> fp32                            [FFN2]
//      3 acc+res -> fp32                                 [W_out fwd]
//      4 acc+res[rev], store at rev -> fp32              [W_out bwd]
// ---------------------------------------------------------------------------
#define BK3 32

template <int AMODE, int EPI>
__global__ __launch_bounds__(256) void gemm3_k(
    const unsigned short* __restrict__ Ah, const unsigned short* __restrict__ Al,
    const unsigned short* __restrict__ Bh, const unsigned short* __restrict__ Bl,
    float* __restrict__ C, unsigned short* __restrict__ Ch,
    unsigned short* __restrict__ Cl, int K, int N,
    const float* __restrict__ bias, const float* __restrict__ res, int ldres) {
    __shared__ unsigned short sm[2][4][128 * BK3];   // [buf][Ah,Al,Bh,Bl] 64 KiB

    const int tid = threadIdx.x;
    const int m0 = blockIdx.y * 128, n0 = blockIdx.x * 128;
    const int lane = tid & 63;
    const int w = tid >> 6, wr = w >> 1, wc = w & 1;
    const int l15 = lane & 15, l4 = lane >> 4;

    floatx4 acc[4][4] = {};

    const int nt = K / BK3;

    auto stage = [&](int buf, int kt) {
        const int k0 = kt * BK3;
        #pragma unroll
        for (int i = 0; i < 2; ++i) {
            const int slot = i * 256 + tid;        // 512 slots of 16B per tile
            const int r = slot >> 2;               // tile row 0..127
            const int cc = (slot & 3) << 3;        // k-chunk offset (elements)
            const size_t ar = AMODE ? (size_t)((m0 + r) ^ 2047) : (size_t)(m0 + r);
            const size_t br = (size_t)(n0 + r);
            gload16(Ah + ar * K + k0 + cc, &sm[buf][0][slot << 3]);
            gload16(Al + ar * K + k0 + cc, &sm[buf][1][slot << 3]);
            gload16(Bh + br * K + k0 + cc, &sm[buf][2][slot << 3]);
            gload16(Bl + br * K + k0 + cc, &sm[buf][3][slot << 3]);
        }
    };

    stage(0, 0);
    __syncthreads();   // compiler emits vmcnt(0) before s_barrier -> staged

    for (int t = 0; t < nt; ++t) {
        const int cur = t & 1;
        if (t + 1 < nt) stage(cur ^ 1, t + 1);

        // frag reads: lane holds row l15 of its 16-row frag, k = l4*8..l4*8+7
        short8 ah[4], alo[4], bh[4], blo[4];
        #pragma unroll
        for (int f = 0; f < 4; ++f) {
            const int ra = (wr * 64 + f * 16 + l15) * BK3 + l4 * 8;
            const int rb = (wc * 64 + f * 16 + l15) * BK3 + l4 * 8;
            ah[f]  = *(const short8*)&sm[cur][0][ra];
            alo[f] = *(const short8*)&sm[cur][1][ra];
            bh[f]  = *(const short8*)&sm[cur][2][rb];
            blo[f] = *(const short8*)&sm[cur][3][rb];
        }
        #pragma unroll
        for (int p = 0; p < 3; ++p)
            #pragma unroll
            for (int mf = 0; mf < 4; ++mf)
                #pragma unroll
                for (int nf = 0; nf < 4; ++nf) {
                    const short8 a = (p == 2) ? alo[mf] : ah[mf];
                    const short8 b = (p == 1) ? blo[nf] : bh[nf];
                    acc[mf][nf] = __builtin_amdgcn_mfma_f32_16x16x32_bf16(
                        a, b, acc[mf][nf], 0, 0, 0);
                }
        __syncthreads();   // drains stage vmcnt + frag lgkm before buffer swap
    }

    // epilogue: D frag layout col=l15, row=l4*4+j (m89/m91 verified)
    #pragma unroll
    for (int mf = 0; mf < 4; ++mf)
        #pragma unroll
        for (int j = 0; j < 4; ++j) {
            const int rr = m0 + wr * 64 + mf * 16 + l4 * 4 + j;
            const int dr = (EPI == 4) ? (rr ^ 2047) : rr;
            #pragma unroll
            for (int nf = 0; nf < 4; ++nf) {
                const int c = n0 + wc * 64 + nf * 16 + l15;
                float v = acc[mf][nf][j];
                if (EPI == 1 || EPI == 2) v += bias[c];
                if (EPI == 2 || EPI == 3 || EPI == 4)
                    v += res[(size_t)dr * ldres + c];
                if (EPI == 1) {
                    v = fmaxf(v, 0.f);
                    unsigned short h, l;
                    split2(v, h, l);
                    Ch[(size_t)rr * N + c] = h;
                    Cl[(size_t)rr * N + c] = l;
                } else {
                    C[(size_t)dr * N + c] = v;
                }
            }
        }
}

// ---------------------------------------------------------------------------
// fp32 VALU GEMM (kept for proj N=80 and delta K=64)
// ---------------------------------------------------------------------------
#define TM 128
#define TN 128
#define TK 16

template <int AMODE, int EPI, bool NG>
__global__ __launch_bounds__(256, 2) void gemm_k(
    const float* __restrict__ A, const float* __restrict__ B,
    float* __restrict__ C, int M, int N, int K, int lda, int ldc,
    const float* __restrict__ bias, const float* __restrict__ res, int ldres) {
    __shared__ float As[TK][TM + 4];
    __shared__ float Bs[TK][TN + 4];

    const int tid = threadIdx.x;
    const int m0 = blockIdx.y * TM;
    const int n0 = blockIdx.x * TN;
    const int tx = tid & 15, ty = tid >> 4;

    float acc[8][8];
    #pragma unroll
    for (int i = 0; i < 8; i++)
        #pragma unroll
        for (int j = 0; j < 8; j++) acc[i][j] = 0.f;

    const int lr  = tid >> 2;
    const int lc4 = (tid & 3) << 2;

    #pragma unroll 1
    for (int kk = 0; kk < K; kk += TK) {
        const int am0 = m0 + lr, am1 = m0 + lr + 64;
        const int sa0 = AMODE ? (am0 ^ 2047) : am0;
        const int sa1 = AMODE ? (am1 ^ 2047) : am1;
        const float4 a0 = *(const float4*)(A + (size_t)sa0 * lda + kk + lc4);
        const float4 a1 = *(const float4*)(A + (size_t)sa1 * lda + kk + lc4);
        float4 b0, b1;
        if (!NG || (n0 + lr) < N)
            b0 = *(const float4*)(B + (size_t)(n0 + lr) * K + kk + lc4);
        else
            b0 = make_float4(0.f, 0.f, 0.f, 0.f);
        if (!NG || (n0 + lr + 64) < N)
            b1 = *(const float4*)(B + (size_t)(n0 + lr + 64) * K + kk + lc4);
        else
            b1 = make_float4(0.f, 0.f, 0.f, 0.f);

        __syncthreads();
        As[lc4 + 0][lr] = a0.x; As[lc4 + 1][lr] = a0.y;
        As[lc4 + 2][lr] = a0.z; As[lc4 + 3][lr] = a0.w;
        As[lc4 + 0][lr + 64] = a1.x; As[lc4 + 1][lr + 64] = a1.y;
        As[lc4 + 2][lr + 64] = a1.z; As[lc4 + 3][lr + 64] = a1.w;
        Bs[lc4 + 0][lr] = b0.x; Bs[lc4 + 1][lr] = b0.y;
        Bs[lc4 + 2][lr] = b0.z; Bs[lc4 + 3][lr] = b0.w;
        Bs[lc4 + 0][lr + 64] = b1.x; Bs[lc4 + 1][lr + 64] = b1.y;
        Bs[lc4 + 2][lr + 64] = b1.z; Bs[lc4 + 3][lr + 64] = b1.w;
        __syncthreads();

        #pragma unroll
        for (int k = 0; k < TK; k++) {
            const float4 a0v = *(const float4*)&As[k][ty * 4];
            const float4 a1v = *(const float4*)&As[k][ty * 4 + 64];
            const float4 b0v = *(const float4*)&Bs[k][tx * 4];
            const float4 b1v = *(const float4*)&Bs[k][tx * 4 + 64];
            const float av[8] = {a0v.x, a0v.y, a0v.z, a0v.w,
                                 a1v.x, a1v.y, a1v.z, a1v.w};
            const float bv[8] = {b0v.x, b0v.y, b0v.z, b0v.w,
                                 b1v.x, b1v.y, b1v.z, b1v.w};
            #pragma unroll
            for (int i = 0; i < 8; i++)
                #pragma unroll
                for (int j = 0; j < 8; j++)
                    acc[i][j] = fmaf(av[i], bv[j], acc[i][j]);
        }
    }

    #pragma unroll
    for (int ih = 0; ih < 2; ih++) {
        #pragma unroll
        for (int ii = 0; ii < 4; ii++) {
            const int i = ih * 4 + ii;
            const int r = m0 + ih * 64 + ty * 4 + ii;
            #pragma unroll
            for (int jh = 0; jh < 2; jh++) {
                const int c0 = n0 + jh * 64 + tx * 4;
                float4 v = make_float4(acc[i][jh * 4 + 0], acc[i][jh * 4 + 1],
                                       acc[i][jh * 4 + 2], acc[i][jh * 4 + 3]);
                if (EPI == 1) {
                    const float4 bi = *(const float4*)(bias + c0);
                    v.x = softplus_f(v.x + bi.x);
                    v.y = softplus_f(v.y + bi.y);
                    v.z = softplus_f(v.z + bi.z);
                    v.w = softplus_f(v.w + bi.w);
                }
                if (!NG || (c0 + 3) < N) {
                    *(float4*)(C + (size_t)r * ldc + c0) = v;
                } else {
                    const float vv[4] = {v.x, v.y, v.z, v.w};
                    #pragma unroll
                    for (int e = 0; e < 4; e++)
                        if (c0 + e < N) C[(size_t)r * ldc + c0 + e] = vv[e];
                }
            }
        }
    }
}

// ---------------------------------------------------------------------------
// Depthwise causal conv (k=2) + SiLU
// ---------------------------------------------------------------------------
__global__ __launch_bounds__(256) void conv_k(const float* __restrict__ xz,
                                              const float* __restrict__ w,
                                              const float* __restrict__ cb,
                                              float* __restrict__ xc) {
    const int idx = blockIdx.x * 256 + threadIdx.x;
    const int t = idx >> 8;
    const int d4 = (idx & 255) << 2;
    const int l = t & (LSEQ - 1);

    const float4 cur = *(const float4*)(xz + (size_t)t * 2048 + d4);
    float4 prev = make_float4(0.f, 0.f, 0.f, 0.f);
    if (l > 0) prev = *(const float4*)(xz + (size_t)(t - 1) * 2048 + d4);

    const float4 wa = *(const float4*)(w + d4 * 2);
    const float4 wb = *(const float4*)(w + d4 * 2 + 4);
    const float4 bb = *(const float4*)(cb + d4);

    float4 o;
    o.x = silu_f(prev.x * wa.x + cur.x * wa.y + bb.x);
    o.y = silu_f(prev.y * wa.z + cur.y * wa.w + bb.y);
    o.z = silu_f(prev.z * wb.x + cur.z * wb.y + bb.z);
    o.w = silu_f(prev.w * wb.z + cur.w * wb.w + bb.w);
    *(float4*)(xc + (size_t)t * DM + d4) = o;
}

// ---------------------------------------------------------------------------
// Selective scan, 3-phase chunked.
// P/S/hin layout: [b][d][chunk][n] = ((b*1024+d)*64 + chunk)*8 + n
// ---------------------------------------------------------------------------
__global__ __launch_bounds__(256) void scanA_k(const float* __restrict__ delta,
                                               const float* __restrict__ xc,
                                               const float* __restrict__ proj,
                                               const float* __restrict__ A_log,
                                               float* __restrict__ P,
                                               float* __restrict__ S) {
    const int bx = blockIdx.x;
    const int dblk = bx & 3;
    const int chunk = (bx >> 2) & 63;
    const int b = bx >> 8;
    const int d = dblk * 256 + threadIdx.x;
    const int t0 = b * LSEQ + chunk * LCHUNK;

    __shared__ float sB[LCHUNK][NSTATE];
    {
        const int l = threadIdx.x >> 3, n = threadIdx.x & 7;
        sB[l][n] = proj[(size_t)(t0 + l) * 80 + 64 + n];
    }
    __syncthreads();

    float nA[8], h[8], Pp[8];
    #pragma unroll
    for (int n = 0; n < 8; n++) {
        nA[n] = -expf(A_log[d * 8 + n]);
        h[n] = 0.f;
        Pp[n] = 1.f;
    }
    for (int l = 0; l < LCHUNK; l++) {
        const int t = t0 + l;
        const float dl = delta[(size_t)t * DM + d];
        const float xcv = xc[(size_t)t * DM + d];
        const float dx = dl * xcv;
        #pragma unroll
        for (int n = 0; n < 8; n++) {
            const float dA = expf(dl * nA[n]);
            h[n] = fmaf(dA, h[n], dx * sB[l][n]);
            Pp[n] *= dA;
        }
    }
    const size_t base = ((size_t)(b * DM + d) * NCHUNK + chunk) * NSTATE;
    #pragma unroll
    for (int n = 0; n < 8; n++) {
        P[base + n] = Pp[n];
        S[base + n] = h[n];
    }
}

__global__ __launch_bounds__(256) void scanB_k(const float* __restrict__ P,
                                               const float* __restrict__ S,
                                               float* __restrict__ hin) {
    const int idx = blockIdx.x * 256 + threadIdx.x;
    const int n = idx & 7;
    const int bd = idx >> 3;
    const size_t base = (size_t)bd * NCHUNK * NSTATE + n;
    float h = 0.f;
    for (int c = 0; c < NCHUNK; c++) {
        const size_t a = base + (size_t)c * NSTATE;
        hin[a] = h;
        h = fmaf(P[a], h, S[a]);
    }
}

__global__ __launch_bounds__(256) void scanC_k(const float* __restrict__ delta,
                                               const float* __restrict__ xc,
                                               const float* __restrict__ proj,
                                               const float* __restrict__ A_log,
                                               const float* __restrict__ Dskip,
                                               const float* __restrict__ xz,
                                               const float* __restrict__ hin,
                                               unsigned short* __restrict__ yh,
                                               unsigned short* __restrict__ yl) {
    const int bx = blockIdx.x;
    const int dblk = bx & 3;
    const int chunk = (bx >> 2) & 63;
    const int b = bx >> 8;
    const int d = dblk * 256 + threadIdx.x;
    const int t0 = b * LSEQ + chunk * LCHUNK;

    __shared__ float sB[LCHUNK][NSTATE];
    __shared__ float sC[LCHUNK][NSTATE];
    {
        const int l = threadIdx.x >> 3, n = threadIdx.x & 7;
        sB[l][n] = proj[(size_t)(t0 + l) * 80 + 64 + n];
        sC[l][n] = proj[(size_t)(t0 + l) * 80 + 72 + n];
    }
    __syncthreads();

    const size_t base = ((size_t)(b * DM + d) * NCHUNK + chunk) * NSTATE;
    float nA[8], h[8];
    #pragma unroll
    for (int n = 0; n < 8; n++) {
        nA[n] = -expf(A_log[d * 8 + n]);
        h[n] = hin[base + n];
    }
    const float dsk = Dskip[d];
    for (int l = 0; l < LCHUNK; l++) {
        const int t = t0 + l;
        const float dl = delta[(size_t)t * DM + d];
        const float xcv = xc[(size_t)t * DM + d];
        const float dx = dl * xcv;
        float yv = 0.f;
        #pragma unroll
        for (int n = 0; n < 8; n++) {
            const float dA = expf(dl * nA[n]);
            h[n] = fmaf(dA, h[n], dx * sB[l][n]);
            yv = fmaf(h[n], sC[l][n], yv);
        }
        const float zv = xz[(size_t)t * 2048 + DM + d];
        const float out = (yv + dsk * xcv) * silu_f(zv);
        unsigned short hh, ll;
        split2(out, hh, ll);
        yh[(size_t)t * DM + d] = hh;
        yl[(size_t)t * DM + d] = ll;
    }
}

// ---------------------------------------------------------------------------
// LayerNorm; optional add; optional bf16 hi/lo emission of the final value
// ---------------------------------------------------------------------------
__global__ __launch_bounds__(256) void ln_k(const float* __restrict__ in,
                                            const float* __restrict__ gamma,
                                            const float* __restrict__ beta,
                                            const float* __restrict__ add,
                                            float* __restrict__ out,
                                            unsigned short* __restrict__ oh,
                                            unsigned short* __restrict__ ol,
                                            int hasAdd) {
    const int row = blockIdx.x;
    const int tid = threadIdx.x;
    const float4 v = *(const float4*)(in + (size_t)row * DM + tid * 4);

    float s = v.x + v.y + v.z + v.w;
    #pragma unroll
    for (int o = 32; o; o >>= 1) s += __shfl_down(s, o);
    __shared__ float red[4];
    if ((tid & 63) == 0) red[tid >> 6] = s;
    __syncthreads();
    const float mu = (red[0] + red[1] + red[2] + red[3]) * (1.f / DM);

    float4 dv;
    dv.x = v.x - mu; dv.y = v.y - mu; dv.z = v.z - mu; dv.w = v.w - mu;
    float s2 = dv.x * dv.x + dv.y * dv.y + dv.z * dv.z + dv.w * dv.w;
    #pragma unroll
    for (int o = 32; o; o >>= 1) s2 += __shfl_down(s2, o);
    __syncthreads();
    if ((tid & 63) == 0) red[tid >> 6] = s2;
    __syncthreads();
    const float var = (red[0] + red[1] + red[2] + red[3]) * (1.f / DM);
    const float rs = rsqrtf(var + 1e-5f);

    const float4 g = *(const float4*)(gamma + tid * 4);
    const float4 bt = *(const float4*)(beta + tid * 4);
    float4 o4;
    o4.x = dv.x * rs * g.x + bt.x;
    o4.y = dv.y * rs * g.y + bt.y;
    o4.z = dv.z * rs * g.z + bt.z;
    o4.w = dv.w * rs * g.w + bt.w;
    if (hasAdd) {
        const float4 a = *(const float4*)(add + (size_t)row * DM + tid * 4);
        o4.x += a.x; o4.y += a.y; o4.z += a.z; o4.w += a.w;
    }
    *(float4*)(out + (size_t)row * DM + tid * 4) = o4;
    if (oh) {
        const size_t i0 = (size_t)row * DM + tid * 4;
        ushort4 h, l;
        split2(o4.x, h.x, l.x);
        split2(o4.y, h.y, l.y);
        split2(o4.z, h.z, l.z);
        split2(o4.w, h.w, l.w);
        *(ushort4*)(oh + i0) = h;
        *(ushort4*)(ol + i0) = l;
    }
}

// ---------------------------------------------------------------------------
// Host-side orchestration
// ---------------------------------------------------------------------------
extern "C" void kernel_launch(void* const* d_in, const int* in_sizes, int n_in,
                              void* d_out, int out_size, void* d_ws,
                              size_t ws_size, hipStream_t stream) {
    const float* x = (const float*)d_in[0];
    auto F = [&](int i) { return (const float*)d_in[i]; };

    float* ws = (float*)d_ws;
    float* xt    = ws + 0;            //  4M floats
    float* xz    = ws + 4194304;      //  8M floats
    float* xc    = ws + 12582912;     //  4M
    float* delta = ws + 16777216;     //  4M
    float* proj  = ws + 20971520;     //  0.33M
    unsigned short* y_h = (unsigned short*)(ws + 21299200);  // 4M ushorts
    unsigned short* y_l = (unsigned short*)(ws + 23396352);
    float* Pb    = ws + 25493504;     //  1M
    float* Sb    = ws + 26542080;     //  1M
    float* hin   = ws + 27590656;     //  1M
    float* osum  = ws + 28639232;     //  4M
    unsigned short* xt_h = (unsigned short*)(ws + 32833536);  // 4M ushorts
    unsigned short* xt_l = (unsigned short*)(ws + 34930688);
    unsigned short* o_h  = xt_h;      // alias: xt_h/l dead after bwd W_in GEMM
    unsigned short* o_l  = xt_l;
    unsigned short* w_h  = (unsigned short*)(ws + 37027840);  // <=4M ushorts
    unsigned short* w_l  = (unsigned short*)(ws + 39124992);
    // FFN1 bf16 outputs alias dead regions: f1_h over xz, f1_l over xc+delta
    unsigned short* f1_h = (unsigned short*)(ws + 4194304);
    unsigned short* f1_l = (unsigned short*)(ws + 12582912);

    float* obuf = (float*)d_out;      // alias: fully rewritten by final LN

    const dim3 blk(256);
    const dim3 gIn(2048 / 128, NTOK / 128);
    const dim3 gSq(1024 / 128, NTOK / 128);
    const dim3 gF1(4096 / 128, NTOK / 128);
    const dim3 gPr(1, NTOK / TM);

    transpose_k<<<dim3(LSEQ / 32, DM / 32, 2), dim3(32, 8), 0, stream>>>(
        x, xt, xt_h, xt_l);

    // ================= forward direction =================
    {
        split_k<<<2048, blk, 0, stream>>>(F(1), w_h, w_l, 2048 * 1024 / 4);
        gemm3_k<0, 0><<<gIn, blk, 0, stream>>>(
            xt_h, xt_l, w_h, w_l, xz, nullptr, nullptr, 1024, 2048,
            nullptr, nullptr, 0);
        conv_k<<<NTOK, blk, 0, stream>>>(xz, F(2), F(3), xc);
        gemm_k<0, 0, true><<<gPr, blk, 0, stream>>>(
            xc, F(4), proj, NTOK, 80, 1024, 1024, 80, nullptr, nullptr, 0);
        gemm_k<0, 1, false><<<dim3(8, 32), blk, 0, stream>>>(
            proj, F(5), delta, NTOK, 1024, 64, 80, 1024, F(6), nullptr, 0);
        scanA_k<<<512, blk, 0, stream>>>(delta, xc, proj, F(7), Pb, Sb);
        scanB_k<<<64, blk, 0, stream>>>(Pb, Sb, hin);
        scanC_k<<<512, blk, 0, stream>>>(delta, xc, proj, F(7), F(8), xz, hin,
                                         y_h, y_l);
        split_k<<<1024, blk, 0, stream>>>(F(9), w_h, w_l, 1024 * 1024 / 4);
        gemm3_k<0, 3><<<gSq, blk, 0, stream>>>(
            y_h, y_l, w_h, w_l, obuf, nullptr, nullptr, 1024, 1024,
            nullptr, xt, 1024);
        ln_k<<<NTOK, blk, 0, stream>>>(obuf, F(19), F(20), nullptr, obuf,
                                       nullptr, nullptr, 0);
    }
    // ================= backward direction =================
    {
        split_k<<<2048, blk, 0, stream>>>(F(10), w_h, w_l, 2048 * 1024 / 4);
        gemm3_k<1, 0><<<gIn, blk, 0, stream>>>(
            xt_h, xt_l, w_h, w_l, xz, nullptr, nullptr, 1024, 2048,
            nullptr, nullptr, 0);
        conv_k<<<NTOK, blk, 0, stream>>>(xz, F(11), F(12), xc);
        gemm_k<0, 0, true><<<gPr, blk, 0, stream>>>(
            xc, F(13), proj, NTOK, 80, 1024, 1024, 80, nullptr, nullptr, 0);
        gemm_k<0, 1, false><<<dim3(8, 32), blk, 0, stream>>>(
            proj, F(14), delta, NTOK, 1024, 64, 80, 1024, F(15), nullptr, 0);
        scanA_k<<<512, blk, 0, stream>>>(delta, xc, proj, F(16), Pb, Sb);
        scanB_k<<<64, blk, 0, stream>>>(Pb, Sb, hin);
        scanC_k<<<512, blk, 0, stream>>>(delta, xc, proj, F(16), F(17), xz, hin,
                                         y_h, y_l);
        split_k<<<1024, blk, 0, stream>>>(F(18), w_h, w_l, 1024 * 1024 / 4);
        // store reversed + add xt at reversed rows -> osum = xt + ob
        gemm3_k<0, 4><<<gSq, blk, 0, stream>>>(
            y_h, y_l, w_h, w_l, osum, nullptr, nullptr, 1024, 1024,
            nullptr, xt, 1024);
        // o = LN(osum)*g+b + obuf -> obuf (+ bf16 hi/lo for FFN1)
        ln_k<<<NTOK, blk, 0, stream>>>(osum, F(21), F(22), obuf, obuf,
                                       o_h, o_l, 1);
    }
    // ================= FFN + final LN =================
    split_k<<<4096, blk, 0, stream>>>(F(25), w_h, w_l, 4096 * 1024 / 4);
    gemm3_k<0, 1><<<gF1, blk, 0, stream>>>(
        o_h, o_l, w_h, w_l, nullptr, f1_h, f1_l, 1024, 4096,
        F(26), nullptr, 0);
    split_k<<<4096, blk, 0, stream>>>(F(27), w_h, w_l, 1024 * 4096 / 4);
    gemm3_k<0, 2><<<gSq, blk, 0, stream>>>(
        f1_h, f1_l, w_h, w_l, osum, nullptr, nullptr, 4096, 1024,
        F(28), obuf, 1024);
    ln_k<<<NTOK, blk, 0, stream>>>(osum, F(23), F(24), nullptr, (float*)d_out,
                                   nullptr, nullptr, 0);
}

// Round 7
// 885.434 us; speedup vs baseline: 1.2130x; 1.2130x over previous
//
#include <hip/hip_runtime.h>
#include <hip/hip_bf16.h>
#include <math.h>
#include <stdint.h>

// ---------------------------------------------------------------------------
// Bidirectional Mamba block + FFN.
// Big GEMMs: split-fp32 (bf16 hi/lo x3) MFMA, 128xBN tile (BN=128 or 64),
//   BK=32, double-buffered LDS via global_load_lds w16, both-sides XOR swizzle.
// Small GEMMs (proj N=80 split-K, delta K=64), conv, scan, LN: fp32 VALU.
// Backward direction via per-lane global-source row index XOR 2047 (L=2048).
// ---------------------------------------------------------------------------

#define NTOK   4096
#define DM     1024
#define LSEQ   2048
#define NSTATE 8
#define NCHUNK 64
#define LCHUNK 32

typedef __attribute__((ext_vector_type(8))) short short8;
typedef __attribute__((ext_vector_type(4))) float floatx4;

__device__ __forceinline__ float softplus_f(float v) {
    return (v > 20.f) ? v : log1pf(__expf(v));
}
__device__ __forceinline__ float silu_f(float v) {
    return v / (1.f + __expf(-v));
}

// bf16 helpers (manual RNE)
__device__ __forceinline__ unsigned short f2bf(float x) {
    union { float f; unsigned int u; } a; a.f = x;
    const unsigned int r = a.u + 0x7fffu + ((a.u >> 16) & 1u);
    return (unsigned short)(r >> 16);
}
__device__ __forceinline__ float bf2f(unsigned short h) {
    union { unsigned int u; float f; } a; a.u = ((unsigned int)h) << 16;
    return a.f;
}
__device__ __forceinline__ void split2(float x, unsigned short& h, unsigned short& l) {
    h = f2bf(x);
    l = f2bf(x - bf2f(h));
}

// async global -> LDS, 16 bytes per lane (dest linear in lane; source carries
// any permutation/swizzle per-lane -- m104/m108/m173).
__device__ __forceinline__ void gload16(const void* g, void* l) {
#if __has_builtin(__builtin_amdgcn_global_load_lds)
    __builtin_amdgcn_global_load_lds(
        reinterpret_cast<const __attribute__((address_space(1))) unsigned int*>(
            reinterpret_cast<uintptr_t>(g)),
        reinterpret_cast<__attribute__((address_space(3))) unsigned int*>(
            reinterpret_cast<uintptr_t>(l)),
        16, 0, 0);
#else
    *reinterpret_cast<uint4*>(l) = *reinterpret_cast<const uint4*>(g);
#endif
}

// ---------------------------------------------------------------------------
// Transpose x (B, D, L) -> xt (B, L, D) fp32 + hi/lo bf16
// ---------------------------------------------------------------------------
__global__ __launch_bounds__(256) void transpose_k(const float* __restrict__ x,
                                                   float* __restrict__ xt,
                                                   unsigned short* __restrict__ xth,
                                                   unsigned short* __restrict__ xtl) {
    __shared__ float tile[32][33];
    const int b  = blockIdx.z;
    const int l0 = blockIdx.x * 32;
    const int d0 = blockIdx.y * 32;
    const int tx = threadIdx.x, ty = threadIdx.y;   // (32, 8)
    const float* src = x + (size_t)b * DM * LSEQ;
    #pragma unroll
    for (int i = 0; i < 4; i++)
        tile[ty + i * 8][tx] = src[(size_t)(d0 + ty + i * 8) * LSEQ + l0 + tx];
    __syncthreads();
    const size_t base = (size_t)b * LSEQ * DM;
    #pragma unroll
    for (int i = 0; i < 4; i++) {
        const float v = tile[tx][ty + i * 8];
        const size_t idx = base + (size_t)(l0 + ty + i * 8) * DM + d0 + tx;
        xt[idx] = v;
        unsigned short h, l;
        split2(v, h, l);
        xth[idx] = h;
        xtl[idx] = l;
    }
}

// ---------------------------------------------------------------------------
// Weight split: fp32 -> hi/lo bf16 (n4 = n/4 float4 groups)
// ---------------------------------------------------------------------------
__global__ __launch_bounds__(256) void split_k(const float* __restrict__ w,
                                               unsigned short* __restrict__ hi,
                                               unsigned short* __restrict__ lo,
                                               int n4) {
    const int i = blockIdx.x * 256 + threadIdx.x;
    if (i >= n4) return;
    const float4 v = ((const float4*)w)[i];
    ushort4 h, l;
    split2(v.x, h.x, l.x);
    split2(v.y, h.y, l.y);
    split2(v.z, h.z, l.z);
    split2(v.w, h.w, l.w);
    ((ushort4*)hi)[i] = h;
    ((ushort4*)lo)[i] = l;
}

// ---------------------------------------------------------------------------
// MFMA split-fp32 GEMM: C[M,N] = A[M,K] @ B[N,K]^T via bf16 hi/lo, 3 MFMA terms.
// BM=128, BN template (128 or 64), BK=32, 256 threads (4 waves).
//   BN=128: waves 2x2 over 64x64 sub-tiles (MF=4). LDS 64 KiB -> 2 blk/CU.
//   BN=64 : waves 4x1 over 32x64 sub-tiles (MF=2). LDS 48 KiB -> 3 blk/CU;
//           used for N=1024 GEMMs so grid = 16x32 = 512 blocks (was 256).
// LDS both-sides swizzle: 16B chunk c of row r lands at c ^ ((r>>1)&3)
// (inverse-swizzled global source + swizzled ds_read; dest stays linear).
// Kills the 8-way bank conflict of the 64 B-stride frag reads -> 2-way (free).
// AMODE: 1 = A row read reversed (row ^ 2047)
// EPI: 0 plain fp32 store
//      1 relu(acc+bias) -> bf16 hi/lo stores (Ch/Cl)     [FFN1]
//      2 acc+bias+res -> fp32                            [FFN2]
//      3 acc+res -> fp32                                 [W_out fwd]
//      4 acc+res[rev], store at rev -> fp32              [W_out bwd]
// ---------------------------------------------------------------------------
template <int AMODE, int EPI, int BN>
__global__ __launch_bounds__(256, 2) void gemm3_k(
    const unsigned short* __restrict__ Ah, const unsigned short* __restrict__ Al,
    const unsigned short* __restrict__ Bh, const unsigned short* __restrict__ Bl,
    float* __restrict__ C, unsigned short* __restrict__ Ch,
    unsigned short* __restrict__ Cl, int K, int N,
    const float* __restrict__ bias, const float* __restrict__ res, int ldres) {
    constexpr int BITER = (BN == 128) ? 2 : 1;   // B stage iterations
    constexpr int MF    = (BN == 128) ? 4 : 2;   // A frags per wave
    constexpr int WROWS = (BN == 128) ? 64 : 32; // rows per wave
    __shared__ unsigned short smA[2][2][128 * 32];
    __shared__ unsigned short smB[2][2][BN * 32];

    const int tid = threadIdx.x;
    const int m0 = blockIdx.y * 128, n0 = blockIdx.x * BN;
    const int lane = tid & 63;
    const int w = tid >> 6;
    const int wr = (BN == 128) ? (w >> 1) : w;
    const int wc = (BN == 128) ? (w & 1) : 0;
    const int l15 = lane & 15, l4 = lane >> 4;

    floatx4 acc[MF][4] = {};

    const int nt = K / 32;

    auto stage = [&](int buf, int kt) {
        const int k0 = kt * 32;
        #pragma unroll
        for (int i = 0; i < 2; ++i) {           // A: 512 slots of 16 B
            const int slot = i * 256 + tid;
            const int r = slot >> 2, c = slot & 3;
            const int cg = c ^ ((r >> 1) & 3);  // inverse swizzle on source
            const size_t ar = AMODE ? (size_t)((m0 + r) ^ 2047) : (size_t)(m0 + r);
            gload16(Ah + ar * K + k0 + cg * 8, &smA[buf][0][slot * 8]);
            gload16(Al + ar * K + k0 + cg * 8, &smA[buf][1][slot * 8]);
        }
        #pragma unroll
        for (int i = 0; i < BITER; ++i) {       // B: BN*4 slots of 16 B
            const int slot = i * 256 + tid;
            const int r = slot >> 2, c = slot & 3;
            const int cg = c ^ ((r >> 1) & 3);
            const size_t br = (size_t)(n0 + r);
            gload16(Bh + br * K + k0 + cg * 8, &smB[buf][0][slot * 8]);
            gload16(Bl + br * K + k0 + cg * 8, &smB[buf][1][slot * 8]);
        }
    };

    // swizzled read offset (ushort units) for row, this lane's k-chunk l4
    auto soff = [&](int row) { return row * 32 + ((l4 ^ ((row >> 1) & 3)) * 8); };

    stage(0, 0);
    __syncthreads();   // compiler emits vmcnt(0) before s_barrier -> staged

    for (int t = 0; t < nt; ++t) {
        const int cur = t & 1;
        if (t + 1 < nt) stage(cur ^ 1, t + 1);

        short8 ah[MF], alo[MF], bh[4], blo[4];
        #pragma unroll
        for (int f = 0; f < MF; ++f) {
            const int arow = wr * WROWS + f * 16 + l15;
            ah[f]  = *(const short8*)&smA[cur][0][soff(arow)];
            alo[f] = *(const short8*)&smA[cur][1][soff(arow)];
        }
        #pragma unroll
        for (int f = 0; f < 4; ++f) {
            const int brow = wc * 64 + f * 16 + l15;
            bh[f]  = *(const short8*)&smB[cur][0][soff(brow)];
            blo[f] = *(const short8*)&smB[cur][1][soff(brow)];
        }
        #pragma unroll
        for (int p = 0; p < 3; ++p)
            #pragma unroll
            for (int mf = 0; mf < MF; ++mf)
                #pragma unroll
                for (int nf = 0; nf < 4; ++nf) {
                    const short8 a = (p == 2) ? alo[mf] : ah[mf];
                    const short8 b = (p == 1) ? blo[nf] : bh[nf];
                    acc[mf][nf] = __builtin_amdgcn_mfma_f32_16x16x32_bf16(
                        a, b, acc[mf][nf], 0, 0, 0);
                }
        __syncthreads();   // drains stage vmcnt + frag lgkm before buffer swap
    }

    // epilogue: D frag layout col=l15, row=l4*4+j (m89/m91 verified)
    #pragma unroll
    for (int mf = 0; mf < MF; ++mf)
        #pragma unroll
        for (int j = 0; j < 4; ++j) {
            const int rr = m0 + wr * WROWS + mf * 16 + l4 * 4 + j;
            const int dr = (EPI == 4) ? (rr ^ 2047) : rr;
            #pragma unroll
            for (int nf = 0; nf < 4; ++nf) {
                const int c = n0 + wc * 64 + nf * 16 + l15;
                float v = acc[mf][nf][j];
                if (EPI == 1 || EPI == 2) v += bias[c];
                if (EPI == 2 || EPI == 3 || EPI == 4)
                    v += res[(size_t)dr * ldres + c];
                if (EPI == 1) {
                    v = fmaxf(v, 0.f);
                    unsigned short h, l;
                    split2(v, h, l);
                    Ch[(size_t)rr * N + c] = h;
                    Cl[(size_t)rr * N + c] = l;
                } else {
                    C[(size_t)dr * N + c] = v;
                }
            }
        }
}

// ---------------------------------------------------------------------------
// fp32 VALU GEMM (proj N=80 with split-K over blockIdx.z, delta K=64)
// kseg = K-slice per z-block; zout = C element offset per z-block.
// ---------------------------------------------------------------------------
#define TM 128
#define TN 128
#define TK 16

template <int AMODE, int EPI, bool NG>
__global__ __launch_bounds__(256, 2) void gemm_k(
    const float* __restrict__ A, const float* __restrict__ B,
    float* __restrict__ C, int M, int N, int K, int lda, int ldc,
    const float* __restrict__ bias, const float* __restrict__ res, int ldres,
    int kseg, int zout) {
    __shared__ float As[TK][TM + 4];
    __shared__ float Bs[TK][TN + 4];

    const int tid = threadIdx.x;
    const int m0 = blockIdx.y * TM;
    const int n0 = blockIdx.x * TN;
    const int kbeg = blockIdx.z * kseg;
    const int kend = kbeg + kseg;
    C += (size_t)blockIdx.z * zout;
    const int tx = tid & 15, ty = tid >> 4;

    float acc[8][8];
    #pragma unroll
    for (int i = 0; i < 8; i++)
        #pragma unroll
        for (int j = 0; j < 8; j++) acc[i][j] = 0.f;

    const int lr  = tid >> 2;
    const int lc4 = (tid & 3) << 2;

    #pragma unroll 1
    for (int kk = kbeg; kk < kend; kk += TK) {
        const int am0 = m0 + lr, am1 = m0 + lr + 64;
        const int sa0 = AMODE ? (am0 ^ 2047) : am0;
        const int sa1 = AMODE ? (am1 ^ 2047) : am1;
        const float4 a0 = *(const float4*)(A + (size_t)sa0 * lda + kk + lc4);
        const float4 a1 = *(const float4*)(A + (size_t)sa1 * lda + kk + lc4);
        float4 b0, b1;
        if (!NG || (n0 + lr) < N)
            b0 = *(const float4*)(B + (size_t)(n0 + lr) * K + kk + lc4);
        else
            b0 = make_float4(0.f, 0.f, 0.f, 0.f);
        if (!NG || (n0 + lr + 64) < N)
            b1 = *(const float4*)(B + (size_t)(n0 + lr + 64) * K + kk + lc4);
        else
            b1 = make_float4(0.f, 0.f, 0.f, 0.f);

        __syncthreads();
        As[lc4 + 0][lr] = a0.x; As[lc4 + 1][lr] = a0.y;
        As[lc4 + 2][lr] = a0.z; As[lc4 + 3][lr] = a0.w;
        As[lc4 + 0][lr + 64] = a1.x; As[lc4 + 1][lr + 64] = a1.y;
        As[lc4 + 2][lr + 64] = a1.z; As[lc4 + 3][lr + 64] = a1.w;
        Bs[lc4 + 0][lr] = b0.x; Bs[lc4 + 1][lr] = b0.y;
        Bs[lc4 + 2][lr] = b0.z; Bs[lc4 + 3][lr] = b0.w;
        Bs[lc4 + 0][lr + 64] = b1.x; Bs[lc4 + 1][lr + 64] = b1.y;
        Bs[lc4 + 2][lr + 64] = b1.z; Bs[lc4 + 3][lr + 64] = b1.w;
        __syncthreads();

        #pragma unroll
        for (int k = 0; k < TK; k++) {
            const float4 a0v = *(const float4*)&As[k][ty * 4];
            const float4 a1v = *(const float4*)&As[k][ty * 4 + 64];
            const float4 b0v = *(const float4*)&Bs[k][tx * 4];
            const float4 b1v = *(const float4*)&Bs[k][tx * 4 + 64];
            const float av[8] = {a0v.x, a0v.y, a0v.z, a0v.w,
                                 a1v.x, a1v.y, a1v.z, a1v.w};
            const float bv[8] = {b0v.x, b0v.y, b0v.z, b0v.w,
                                 b1v.x, b1v.y, b1v.z, b1v.w};
            #pragma unroll
            for (int i = 0; i < 8; i++)
                #pragma unroll
                for (int j = 0; j < 8; j++)
                    acc[i][j] = fmaf(av[i], bv[j], acc[i][j]);
        }
    }

    #pragma unroll
    for (int ih = 0; ih < 2; ih++) {
        #pragma unroll
        for (int ii = 0; ii < 4; ii++) {
            const int i = ih * 4 + ii;
            const int r = m0 + ih * 64 + ty * 4 + ii;
            #pragma unroll
            for (int jh = 0; jh < 2; jh++) {
                const int c0 = n0 + jh * 64 + tx * 4;
                float4 v = make_float4(acc[i][jh * 4 + 0], acc[i][jh * 4 + 1],
                                       acc[i][jh * 4 + 2], acc[i][jh * 4 + 3]);
                if (EPI == 1) {
                    const float4 bi = *(const float4*)(bias + c0);
                    v.x = softplus_f(v.x + bi.x);
                    v.y = softplus_f(v.y + bi.y);
                    v.z = softplus_f(v.z + bi.z);
                    v.w = softplus_f(v.w + bi.w);
                }
                if (!NG || (c0 + 3) < N) {
                    *(float4*)(C + (size_t)r * ldc + c0) = v;
                } else {
                    const float vv[4] = {v.x, v.y, v.z, v.w};
                    #pragma unroll
                    for (int e = 0; e < 4; e++)
                        if (c0 + e < N) C[(size_t)r * ldc + c0 + e] = vv[e];
                }
            }
        }
    }
}

// ---------------------------------------------------------------------------
// Sum 8 split-K partials (proj): out[i] = sum_z pp[z*327680 + i], float4 i
// ---------------------------------------------------------------------------
__global__ __launch_bounds__(256) void reduce8_k(const float* __restrict__ pp,
                                                 float* __restrict__ out) {
    const int i = blockIdx.x * 256 + threadIdx.x;   // float4 index, n4 = 81920
    float4 s = ((const float4*)pp)[i];
    #pragma unroll
    for (int z = 1; z < 8; ++z) {
        const float4 v = ((const float4*)(pp + (size_t)z * 327680))[i];
        s.x += v.x; s.y += v.y; s.z += v.z; s.w += v.w;
    }
    ((float4*)out)[i] = s;
}

// ---------------------------------------------------------------------------
// Depthwise causal conv (k=2) + SiLU
// ---------------------------------------------------------------------------
__global__ __launch_bounds__(256) void conv_k(const float* __restrict__ xz,
                                              const float* __restrict__ w,
                                              const float* __restrict__ cb,
                                              float* __restrict__ xc) {
    const int idx = blockIdx.x * 256 + threadIdx.x;
    const int t = idx >> 8;
    const int d4 = (idx & 255) << 2;
    const int l = t & (LSEQ - 1);

    const float4 cur = *(const float4*)(xz + (size_t)t * 2048 + d4);
    float4 prev = make_float4(0.f, 0.f, 0.f, 0.f);
    if (l > 0) prev = *(const float4*)(xz + (size_t)(t - 1) * 2048 + d4);

    const float4 wa = *(const float4*)(w + d4 * 2);
    const float4 wb = *(const float4*)(w + d4 * 2 + 4);
    const float4 bb = *(const float4*)(cb + d4);

    float4 o;
    o.x = silu_f(prev.x * wa.x + cur.x * wa.y + bb.x);
    o.y = silu_f(prev.y * wa.z + cur.y * wa.w + bb.y);
    o.z = silu_f(prev.z * wb.x + cur.z * wb.y + bb.z);
    o.w = silu_f(prev.w * wb.z + cur.w * wb.w + bb.w);
    *(float4*)(xc + (size_t)t * DM + d4) = o;
}

// ---------------------------------------------------------------------------
// Selective scan, 3-phase chunked.
// P/S/hin layout: [b][d][chunk][n] = ((b*1024+d)*64 + chunk)*8 + n
// ---------------------------------------------------------------------------
__global__ __launch_bounds__(256) void scanA_k(const float* __restrict__ delta,
                                               const float* __restrict__ xc,
                                               const float* __restrict__ proj,
                                               const float* __restrict__ A_log,
                                               float* __restrict__ P,
                                               float* __restrict__ S) {
    const int bx = blockIdx.x;
    const int dblk = bx & 3;
    const int chunk = (bx >> 2) & 63;
    const int b = bx >> 8;
    const int d = dblk * 256 + threadIdx.x;
    const int t0 = b * LSEQ + chunk * LCHUNK;

    __shared__ float sB[LCHUNK][NSTATE];
    {
        const int l = threadIdx.x >> 3, n = threadIdx.x & 7;
        sB[l][n] = proj[(size_t)(t0 + l) * 80 + 64 + n];
    }
    __syncthreads();

    float nA[8], h[8], Pp[8];
    #pragma unroll
    for (int n = 0; n < 8; n++) {
        nA[n] = -expf(A_log[d * 8 + n]);
        h[n] = 0.f;
        Pp[n] = 1.f;
    }
    for (int l = 0; l < LCHUNK; l++) {
        const int t = t0 + l;
        const float dl = delta[(size_t)t * DM + d];
        const float xcv = xc[(size_t)t * DM + d];
        const float dx = dl * xcv;
        #pragma unroll
        for (int n = 0; n < 8; n++) {
            const float dA = expf(dl * nA[n]);
            h[n] = fmaf(dA, h[n], dx * sB[l][n]);
            Pp[n] *= dA;
        }
    }
    const size_t base = ((size_t)(b * DM + d) * NCHUNK + chunk) * NSTATE;
    #pragma unroll
    for (int n = 0; n < 8; n++) {
        P[base + n] = Pp[n];
        S[base + n] = h[n];
    }
}

__global__ __launch_bounds__(256) void scanB_k(const float* __restrict__ P,
                                               const float* __restrict__ S,
                                               float* __restrict__ hin) {
    const int idx = blockIdx.x * 256 + threadIdx.x;
    const int n = idx & 7;
    const int bd = idx >> 3;
    const size_t base = (size_t)bd * NCHUNK * NSTATE + n;
    float h = 0.f;
    for (int c = 0; c < NCHUNK; c++) {
        const size_t a = base + (size_t)c * NSTATE;
        hin[a] = h;
        h = fmaf(P[a], h, S[a]);
    }
}

__global__ __launch_bounds__(256) void scanC_k(const float* __restrict__ delta,
                                               const float* __restrict__ xc,
                                               const float* __restrict__ proj,
                                               const float* __restrict__ A_log,
                                               const float* __restrict__ Dskip,
                                               const float* __restrict__ xz,
                                               const float* __restrict__ hin,
                                               unsigned short* __restrict__ yh,
                                               unsigned short* __restrict__ yl) {
    const int bx = blockIdx.x;
    const int dblk = bx & 3;
    const int chunk = (bx >> 2) & 63;
    const int b = bx >> 8;
    const int d = dblk * 256 + threadIdx.x;
    const int t0 = b * LSEQ + chunk * LCHUNK;

    __shared__ float sB[LCHUNK][NSTATE];
    __shared__ float sC[LCHUNK][NSTATE];
    {
        const int l = threadIdx.x >> 3, n = threadIdx.x & 7;
        sB[l][n] = proj[(size_t)(t0 + l) * 80 + 64 + n];
        sC[l][n] = proj[(size_t)(t0 + l) * 80 + 72 + n];
    }
    __syncthreads();

    const size_t base = ((size_t)(b * DM + d) * NCHUNK + chunk) * NSTATE;
    float nA[8], h[8];
    #pragma unroll
    for (int n = 0; n < 8; n++) {
        nA[n] = -expf(A_log[d * 8 + n]);
        h[n] = hin[base + n];
    }
    const float dsk = Dskip[d];
    for (int l = 0; l < LCHUNK; l++) {
        const int t = t0 + l;
        const float dl = delta[(size_t)t * DM + d];
        const float xcv = xc[(size_t)t * DM + d];
        const float dx = dl * xcv;
        float yv = 0.f;
        #pragma unroll
        for (int n = 0; n < 8; n++) {
            const float dA = expf(dl * nA[n]);
            h[n] = fmaf(dA, h[n], dx * sB[l][n]);
            yv = fmaf(h[n], sC[l][n], yv);
        }
        const float zv = xz[(size_t)t * 2048 + DM + d];
        const float out = (yv + dsk * xcv) * silu_f(zv);
        unsigned short hh, ll;
        split2(out, hh, ll);
        yh[(size_t)t * DM + d] = hh;
        yl[(size_t)t * DM + d] = ll;
    }
}

// ---------------------------------------------------------------------------
// LayerNorm; optional add; optional bf16 hi/lo emission of the final value
// ---------------------------------------------------------------------------
__global__ __launch_bounds__(256) void ln_k(const float* __restrict__ in,
                                            const float* __restrict__ gamma,
                                            const float* __restrict__ beta,
                                            const float* __restrict__ add,
                                            float* __restrict__ out,
                                            unsigned short* __restrict__ oh,
                                            unsigned short* __restrict__ ol,
                                            int hasAdd) {
    const int row = blockIdx.x;
    const int tid = threadIdx.x;
    const float4 v = *(const float4*)(in + (size_t)row * DM + tid * 4);

    float s = v.x + v.y + v.z + v.w;
    #pragma unroll
    for (int o = 32; o; o >>= 1) s += __shfl_down(s, o);
    __shared__ float red[4];
    if ((tid & 63) == 0) red[tid >> 6] = s;
    __syncthreads();
    const float mu = (red[0] + red[1] + red[2] + red[3]) * (1.f / DM);

    float4 dv;
    dv.x = v.x - mu; dv.y = v.y - mu; dv.z = v.z - mu; dv.w = v.w - mu;
    float s2 = dv.x * dv.x + dv.y * dv.y + dv.z * dv.z + dv.w * dv.w;
    #pragma unroll
    for (int o = 32; o; o >>= 1) s2 += __shfl_down(s2, o);
    __syncthreads();
    if ((tid & 63) == 0) red[tid >> 6] = s2;
    __syncthreads();
    const float var = (red[0] + red[1] + red[2] + red[3]) * (1.f / DM);
    const float rs = rsqrtf(var + 1e-5f);

    const float4 g = *(const float4*)(gamma + tid * 4);
    const float4 bt = *(const float4*)(beta + tid * 4);
    float4 o4;
    o4.x = dv.x * rs * g.x + bt.x;
    o4.y = dv.y * rs * g.y + bt.y;
    o4.z = dv.z * rs * g.z + bt.z;
    o4.w = dv.w * rs * g.w + bt.w;
    if (hasAdd) {
        const float4 a = *(const float4*)(add + (size_t)row * DM + tid * 4);
        o4.x += a.x; o4.y += a.y; o4.z += a.z; o4.w += a.w;
    }
    *(float4*)(out + (size_t)row * DM + tid * 4) = o4;
    if (oh) {
        const size_t i0 = (size_t)row * DM + tid * 4;
        ushort4 h, l;
        split2(o4.x, h.x, l.x);
        split2(o4.y, h.y, l.y);
        split2(o4.z, h.z, l.z);
        split2(o4.w, h.w, l.w);
        *(ushort4*)(oh + i0) = h;
        *(ushort4*)(ol + i0) = l;
    }
}

// ---------------------------------------------------------------------------
// Host-side orchestration
// ---------------------------------------------------------------------------
extern "C" void kernel_launch(void* const* d_in, const int* in_sizes, int n_in,
                              void* d_out, int out_size, void* d_ws,
                              size_t ws_size, hipStream_t stream) {
    const float* x = (const float*)d_in[0];
    auto F = [&](int i) { return (const float*)d_in[i]; };

    float* ws = (float*)d_ws;
    float* xt    = ws + 0;            //  4M floats
    float* xz    = ws + 4194304;      //  8M floats
    float* xc    = ws + 12582912;     //  4M
    float* delta = ws + 16777216;     //  4M
    float* proj  = ws + 20971520;     //  0.33M
    unsigned short* y_h = (unsigned short*)(ws + 21299200);  // 4M ushorts
    unsigned short* y_l = (unsigned short*)(ws + 23396352);
    float* Pb    = ws + 25493504;     //  1M
    float* Sb    = ws + 26542080;     //  1M
    float* hin   = ws + 27590656;     //  1M
    float* osum  = ws + 28639232;     //  4M
    float* pp    = osum;              // alias: proj split-K partials (2.62M),
                                      // osum not live until bwd W_out
    unsigned short* xt_h = (unsigned short*)(ws + 32833536);  // 4M ushorts
    unsigned short* xt_l = (unsigned short*)(ws + 34930688);
    unsigned short* o_h  = xt_h;      // alias: xt_h/l dead after bwd W_in GEMM
    unsigned short* o_l  = xt_l;
    unsigned short* w_h  = (unsigned short*)(ws + 37027840);  // <=4M ushorts
    unsigned short* w_l  = (unsigned short*)(ws + 39124992);
    // FFN1 bf16 outputs alias dead regions: f1_h over xz, f1_l over xc+delta
    unsigned short* f1_h = (unsigned short*)(ws + 4194304);
    unsigned short* f1_l = (unsigned short*)(ws + 12582912);

    float* obuf = (float*)d_out;      // alias: fully rewritten by final LN

    const dim3 blk(256);
    const dim3 gIn(2048 / 128, NTOK / 128);      // W_in, BN=128: 512 blocks
    const dim3 gSq64(1024 / 64, NTOK / 128);     // N=1024, BN=64: 512 blocks
    const dim3 gF1(4096 / 128, NTOK / 128);      // FFN1, BN=128: 1024 blocks
    const dim3 gPr(1, NTOK / TM, 8);             // proj split-K: 256 blocks
    const dim3 gDt(8, NTOK / TM);                // delta: 256 blocks

    transpose_k<<<dim3(LSEQ / 32, DM / 32, 2), dim3(32, 8), 0, stream>>>(
        x, xt, xt_h, xt_l);

    // ================= forward direction =================
    {
        split_k<<<2048, blk, 0, stream>>>(F(1), w_h, w_l, 2048 * 1024 / 4);
        gemm3_k<0, 0, 128><<<gIn, blk, 0, stream>>>(
            xt_h, xt_l, w_h, w_l, xz, nullptr, nullptr, 1024, 2048,
            nullptr, nullptr, 0);
        conv_k<<<NTOK, blk, 0, stream>>>(xz, F(2), F(3), xc);
        gemm_k<0, 0, true><<<gPr, blk, 0, stream>>>(
            xc, F(4), pp, NTOK, 80, 1024, 1024, 80, nullptr, nullptr, 0,
            128, 327680);
        reduce8_k<<<320, blk, 0, stream>>>(pp, proj);
        gemm_k<0, 1, false><<<gDt, blk, 0, stream>>>(
            proj, F(5), delta, NTOK, 1024, 64, 80, 1024, F(6), nullptr, 0,
            64, 0);
        scanA_k<<<512, blk, 0, stream>>>(delta, xc, proj, F(7), Pb, Sb);
        scanB_k<<<64, blk, 0, stream>>>(Pb, Sb, hin);
        scanC_k<<<512, blk, 0, stream>>>(delta, xc, proj, F(7), F(8), xz, hin,
                                         y_h, y_l);
        split_k<<<1024, blk, 0, stream>>>(F(9), w_h, w_l, 1024 * 1024 / 4);
        gemm3_k<0, 3, 64><<<gSq64, blk, 0, stream>>>(
            y_h, y_l, w_h, w_l, obuf, nullptr, nullptr, 1024, 1024,
            nullptr, xt, 1024);
        ln_k<<<NTOK, blk, 0, stream>>>(obuf, F(19), F(20), nullptr, obuf,
                                       nullptr, nullptr, 0);
    }
    // ================= backward direction =================
    {
        split_k<<<2048, blk, 0, stream>>>(F(10), w_h, w_l, 2048 * 1024 / 4);
        gemm3_k<1, 0, 128><<<gIn, blk, 0, stream>>>(
            xt_h, xt_l, w_h, w_l, xz, nullptr, nullptr, 1024, 2048,
            nullptr, nullptr, 0);
        conv_k<<<NTOK, blk, 0, stream>>>(xz, F(11), F(12), xc);
        gemm_k<0, 0, true><<<gPr, blk, 0, stream>>>(
            xc, F(13), pp, NTOK, 80, 1024, 1024, 80, nullptr, nullptr, 0,
            128, 327680);
        reduce8_k<<<320, blk, 0, stream>>>(pp, proj);
        gemm_k<0, 1, false><<<gDt, blk, 0, stream>>>(
            proj, F(14), delta, NTOK, 1024, 64, 80, 1024, F(15), nullptr, 0,
            64, 0);
        scanA_k<<<512, blk, 0, stream>>>(delta, xc, proj, F(16), Pb, Sb);
        scanB_k<<<64, blk, 0, stream>>>(Pb, Sb, hin);
        scanC_k<<<512, blk, 0, stream>>>(delta, xc, proj, F(16), F(17), xz, hin,
                                         y_h, y_l);
        split_k<<<1024, blk, 0, stream>>>(F(18), w_h, w_l, 1024 * 1024 / 4);
        // store reversed + add xt at reversed rows -> osum = xt + ob
        gemm3_k<0, 4, 64><<<gSq64, blk, 0, stream>>>(
            y_h, y_l, w_h, w_l, osum, nullptr, nullptr, 1024, 1024,
            nullptr, xt, 1024);
        // o = LN(osum)*g+b + obuf -> obuf (+ bf16 hi/lo for FFN1)
        ln_k<<<NTOK, blk, 0, stream>>>(osum, F(21), F(22), obuf, obuf,
                                       o_h, o_l, 1);
    }
    // ================= FFN + final LN =================
    split_k<<<4096, blk, 0, stream>>>(F(25), w_h, w_l, 4096 * 1024 / 4);
    gemm3_k<0, 1, 128><<<gF1, blk, 0, stream>>>(
        o_h, o_l, w_h, w_l, nullptr, f1_h, f1_l, 1024, 4096,
        F(26), nullptr, 0);
    split_k<<<4096, blk, 0, stream>>>(F(27), w_h, w_l, 1024 * 4096 / 4);
    gemm3_k<0, 2, 64><<<gSq64, blk, 0, stream>>>(
        f1_h, f1_l, w_h, w_l, osum, nullptr, nullptr, 4096, 1024,
        F(28), obuf, 1024);
    ln_k<<<NTOK, blk, 0, stream>>>(osum, F(23), F(24), nullptr, (float*)d_out,
                                   nullptr, nullptr, 0);
}

// Round 8
// 840.295 us; speedup vs baseline: 1.2782x; 1.0537x over previous
//
#include <hip/hip_runtime.h>
#include <hip/hip_bf16.h>
#include <math.h>
#include <stdint.h>

// ---------------------------------------------------------------------------
// Bidirectional Mamba block + FFN.
// Big GEMMs: split-fp32 (bf16 hi/lo x3) MFMA, 128xBN tile (BN=128 or 64),
//   BK=32, double-buffered LDS via global_load_lds w16, both-sides XOR swizzle,
//   XCD-chunked block swizzle (n-inner) for L2 locality.
// Small GEMMs (proj N=80 split-K, delta K=64), conv, scan, LN: fp32 VALU.
// Backward direction via per-lane global-source row index XOR 2047 (L=2048).
// ---------------------------------------------------------------------------

#define NTOK   4096
#define DM     1024
#define LSEQ   2048
#define NSTATE 8
#define NCHUNK 64
#define LCHUNK 32

typedef __attribute__((ext_vector_type(8))) short short8;
typedef __attribute__((ext_vector_type(4))) float floatx4;

__device__ __forceinline__ float softplus_f(float v) {
    return (v > 20.f) ? v : log1pf(__expf(v));
}
__device__ __forceinline__ float silu_f(float v) {
    return v / (1.f + __expf(-v));
}

// bf16 helpers (manual RNE)
__device__ __forceinline__ unsigned short f2bf(float x) {
    union { float f; unsigned int u; } a; a.f = x;
    const unsigned int r = a.u + 0x7fffu + ((a.u >> 16) & 1u);
    return (unsigned short)(r >> 16);
}
__device__ __forceinline__ float bf2f(unsigned short h) {
    union { unsigned int u; float f; } a; a.u = ((unsigned int)h) << 16;
    return a.f;
}
__device__ __forceinline__ void split2(float x, unsigned short& h, unsigned short& l) {
    h = f2bf(x);
    l = f2bf(x - bf2f(h));
}

// async global -> LDS, 16 bytes per lane (dest linear in lane; source carries
// any permutation/swizzle per-lane -- m104/m108/m173).
__device__ __forceinline__ void gload16(const void* g, void* l) {
#if __has_builtin(__builtin_amdgcn_global_load_lds)
    __builtin_amdgcn_global_load_lds(
        reinterpret_cast<const __attribute__((address_space(1))) unsigned int*>(
            reinterpret_cast<uintptr_t>(g)),
        reinterpret_cast<__attribute__((address_space(3))) unsigned int*>(
            reinterpret_cast<uintptr_t>(l)),
        16, 0, 0);
#else
    *reinterpret_cast<uint4*>(l) = *reinterpret_cast<const uint4*>(g);
#endif
}

// ---------------------------------------------------------------------------
// Transpose x (B, D, L) -> xt (B, L, D) fp32 + hi/lo bf16
// ---------------------------------------------------------------------------
__global__ __launch_bounds__(256) void transpose_k(const float* __restrict__ x,
                                                   float* __restrict__ xt,
                                                   unsigned short* __restrict__ xth,
                                                   unsigned short* __restrict__ xtl) {
    __shared__ float tile[32][33];
    const int b  = blockIdx.z;
    const int l0 = blockIdx.x * 32;
    const int d0 = blockIdx.y * 32;
    const int tx = threadIdx.x, ty = threadIdx.y;   // (32, 8)
    const float* src = x + (size_t)b * DM * LSEQ;
    #pragma unroll
    for (int i = 0; i < 4; i++)
        tile[ty + i * 8][tx] = src[(size_t)(d0 + ty + i * 8) * LSEQ + l0 + tx];
    __syncthreads();
    const size_t base = (size_t)b * LSEQ * DM;
    #pragma unroll
    for (int i = 0; i < 4; i++) {
        const float v = tile[tx][ty + i * 8];
        const size_t idx = base + (size_t)(l0 + ty + i * 8) * DM + d0 + tx;
        xt[idx] = v;
        unsigned short h, l;
        split2(v, h, l);
        xth[idx] = h;
        xtl[idx] = l;
    }
}

// ---------------------------------------------------------------------------
// Weight split: fp32 -> hi/lo bf16 (n4 = n/4 float4 groups)
// ---------------------------------------------------------------------------
__global__ __launch_bounds__(256) void split_k(const float* __restrict__ w,
                                               unsigned short* __restrict__ hi,
                                               unsigned short* __restrict__ lo,
                                               int n4) {
    const int i = blockIdx.x * 256 + threadIdx.x;
    if (i >= n4) return;
    const float4 v = ((const float4*)w)[i];
    ushort4 h, l;
    split2(v.x, h.x, l.x);
    split2(v.y, h.y, l.y);
    split2(v.z, h.z, l.z);
    split2(v.w, h.w, l.w);
    ((ushort4*)hi)[i] = h;
    ((ushort4*)lo)[i] = l;
}

// ---------------------------------------------------------------------------
// MFMA split-fp32 GEMM: C[M,N] = A[M,K] @ B[N,K]^T via bf16 hi/lo, 3 MFMA terms.
// BM=128, BN template (128 or 64), BK=32, 256 threads (4 waves).
// LDS both-sides swizzle: 16B chunk c of row r lands at c ^ ((r>>1)&3).
// XCD-chunked block swizzle: lin = (bid&7)*(nwg/8) + bid>>3, n-inner order;
// each XCD gets a contiguous m-band so A panels stay L2-resident (T1/m204).
// AMODE: 1 = A row read reversed (row ^ 2047)
// EPI: 0 plain fp32 store
//      1 relu(acc+bias) -> bf16 hi/lo stores (Ch/Cl)     [FFN1]
//      2 acc+bias+res -> fp32                            [FFN2]
//      3 acc+res -> fp32                                 [W_out fwd]
//      4 acc+res[rev], store at rev -> fp32              [W_out bwd]
// ---------------------------------------------------------------------------
template <int AMODE, int EPI, int BN>
__global__ __launch_bounds__(256, 2) void gemm3_k(
    const unsigned short* __restrict__ Ah, const unsigned short* __restrict__ Al,
    const unsigned short* __restrict__ Bh, const unsigned short* __restrict__ Bl,
    float* __restrict__ C, unsigned short* __restrict__ Ch,
    unsigned short* __restrict__ Cl, int K, int N,
    const float* __restrict__ bias, const float* __restrict__ res, int ldres) {
    constexpr int BITER = (BN == 128) ? 2 : 1;   // B stage iterations
    constexpr int MF    = (BN == 128) ? 4 : 2;   // A frags per wave
    constexpr int WROWS = (BN == 128) ? 64 : 32; // rows per wave
    __shared__ unsigned short smA[2][2][128 * 32];
    __shared__ unsigned short smB[2][2][BN * 32];

    const int tid = threadIdx.x;
    // XCD-chunked bijective swizzle (nwg % 8 == 0 for all grids used here).
    // Linear order is n-fastest, so an XCD's contiguous chunk = m-band x all n.
    const int nwg = gridDim.x * gridDim.y;
    const int bid = blockIdx.y * gridDim.x + blockIdx.x;
    const int lin = (bid & 7) * (nwg >> 3) + (bid >> 3);
    const int m0 = (lin / gridDim.x) * 128;
    const int n0 = (lin % gridDim.x) * BN;
    const int lane = tid & 63;
    const int w = tid >> 6;
    const int wr = (BN == 128) ? (w >> 1) : w;
    const int wc = (BN == 128) ? (w & 1) : 0;
    const int l15 = lane & 15, l4 = lane >> 4;

    floatx4 acc[MF][4] = {};

    const int nt = K / 32;

    auto stage = [&](int buf, int kt) {
        const int k0 = kt * 32;
        #pragma unroll
        for (int i = 0; i < 2; ++i) {           // A: 512 slots of 16 B
            const int slot = i * 256 + tid;
            const int r = slot >> 2, c = slot & 3;
            const int cg = c ^ ((r >> 1) & 3);  // inverse swizzle on source
            const size_t ar = AMODE ? (size_t)((m0 + r) ^ 2047) : (size_t)(m0 + r);
            gload16(Ah + ar * K + k0 + cg * 8, &smA[buf][0][slot * 8]);
            gload16(Al + ar * K + k0 + cg * 8, &smA[buf][1][slot * 8]);
        }
        #pragma unroll
        for (int i = 0; i < BITER; ++i) {       // B: BN*4 slots of 16 B
            const int slot = i * 256 + tid;
            const int r = slot >> 2, c = slot & 3;
            const int cg = c ^ ((r >> 1) & 3);
            const size_t br = (size_t)(n0 + r);
            gload16(Bh + br * K + k0 + cg * 8, &smB[buf][0][slot * 8]);
            gload16(Bl + br * K + k0 + cg * 8, &smB[buf][1][slot * 8]);
        }
    };

    // swizzled read offset (ushort units) for row, this lane's k-chunk l4
    auto soff = [&](int row) { return row * 32 + ((l4 ^ ((row >> 1) & 3)) * 8); };

    stage(0, 0);
    __syncthreads();   // compiler emits vmcnt(0) before s_barrier -> staged

    for (int t = 0; t < nt; ++t) {
        const int cur = t & 1;
        if (t + 1 < nt) stage(cur ^ 1, t + 1);

        short8 ah[MF], alo[MF], bh[4], blo[4];
        #pragma unroll
        for (int f = 0; f < MF; ++f) {
            const int arow = wr * WROWS + f * 16 + l15;
            ah[f]  = *(const short8*)&smA[cur][0][soff(arow)];
            alo[f] = *(const short8*)&smA[cur][1][soff(arow)];
        }
        #pragma unroll
        for (int f = 0; f < 4; ++f) {
            const int brow = wc * 64 + f * 16 + l15;
            bh[f]  = *(const short8*)&smB[cur][0][soff(brow)];
            blo[f] = *(const short8*)&smB[cur][1][soff(brow)];
        }
        #pragma unroll
        for (int p = 0; p < 3; ++p)
            #pragma unroll
            for (int mf = 0; mf < MF; ++mf)
                #pragma unroll
                for (int nf = 0; nf < 4; ++nf) {
                    const short8 a = (p == 2) ? alo[mf] : ah[mf];
                    const short8 b = (p == 1) ? blo[nf] : bh[nf];
                    acc[mf][nf] = __builtin_amdgcn_mfma_f32_16x16x32_bf16(
                        a, b, acc[mf][nf], 0, 0, 0);
                }
        __syncthreads();   // drains stage vmcnt + frag lgkm before buffer swap
    }

    // epilogue: D frag layout col=l15, row=l4*4+j (m89/m91 verified)
    #pragma unroll
    for (int mf = 0; mf < MF; ++mf)
        #pragma unroll
        for (int j = 0; j < 4; ++j) {
            const int rr = m0 + wr * WROWS + mf * 16 + l4 * 4 + j;
            const int dr = (EPI == 4) ? (rr ^ 2047) : rr;
            #pragma unroll
            for (int nf = 0; nf < 4; ++nf) {
                const int c = n0 + wc * 64 + nf * 16 + l15;
                float v = acc[mf][nf][j];
                if (EPI == 1 || EPI == 2) v += bias[c];
                if (EPI == 2 || EPI == 3 || EPI == 4)
                    v += res[(size_t)dr * ldres + c];
                if (EPI == 1) {
                    v = fmaxf(v, 0.f);
                    unsigned short h, l;
                    split2(v, h, l);
                    Ch[(size_t)rr * N + c] = h;
                    Cl[(size_t)rr * N + c] = l;
                } else {
                    C[(size_t)dr * N + c] = v;
                }
            }
        }
}

// ---------------------------------------------------------------------------
// fp32 VALU GEMM (proj N=80 with split-K over blockIdx.z, delta K=64)
// kseg = K-slice per z-block; zout = C element offset per z-block.
// ---------------------------------------------------------------------------
#define TM 128
#define TN 128
#define TK 16

template <int AMODE, int EPI, bool NG>
__global__ __launch_bounds__(256, 2) void gemm_k(
    const float* __restrict__ A, const float* __restrict__ B,
    float* __restrict__ C, int M, int N, int K, int lda, int ldc,
    const float* __restrict__ bias, const float* __restrict__ res, int ldres,
    int kseg, int zout) {
    __shared__ float As[TK][TM + 4];
    __shared__ float Bs[TK][TN + 4];

    const int tid = threadIdx.x;
    const int m0 = blockIdx.y * TM;
    const int n0 = blockIdx.x * TN;
    const int kbeg = blockIdx.z * kseg;
    const int kend = kbeg + kseg;
    C += (size_t)blockIdx.z * zout;
    const int tx = tid & 15, ty = tid >> 4;

    float acc[8][8];
    #pragma unroll
    for (int i = 0; i < 8; i++)
        #pragma unroll
        for (int j = 0; j < 8; j++) acc[i][j] = 0.f;

    const int lr  = tid >> 2;
    const int lc4 = (tid & 3) << 2;

    #pragma unroll 1
    for (int kk = kbeg; kk < kend; kk += TK) {
        const int am0 = m0 + lr, am1 = m0 + lr + 64;
        const int sa0 = AMODE ? (am0 ^ 2047) : am0;
        const int sa1 = AMODE ? (am1 ^ 2047) : am1;
        const float4 a0 = *(const float4*)(A + (size_t)sa0 * lda + kk + lc4);
        const float4 a1 = *(const float4*)(A + (size_t)sa1 * lda + kk + lc4);
        float4 b0, b1;
        if (!NG || (n0 + lr) < N)
            b0 = *(const float4*)(B + (size_t)(n0 + lr) * K + kk + lc4);
        else
            b0 = make_float4(0.f, 0.f, 0.f, 0.f);
        if (!NG || (n0 + lr + 64) < N)
            b1 = *(const float4*)(B + (size_t)(n0 + lr + 64) * K + kk + lc4);
        else
            b1 = make_float4(0.f, 0.f, 0.f, 0.f);

        __syncthreads();
        As[lc4 + 0][lr] = a0.x; As[lc4 + 1][lr] = a0.y;
        As[lc4 + 2][lr] = a0.z; As[lc4 + 3][lr] = a0.w;
        As[lc4 + 0][lr + 64] = a1.x; As[lc4 + 1][lr + 64] = a1.y;
        As[lc4 + 2][lr + 64] = a1.z; As[lc4 + 3][lr + 64] = a1.w;
        Bs[lc4 + 0][lr] = b0.x; Bs[lc4 + 1][lr] = b0.y;
        Bs[lc4 + 2][lr] = b0.z; Bs[lc4 + 3][lr] = b0.w;
        Bs[lc4 + 0][lr + 64] = b1.x; Bs[lc4 + 1][lr + 64] = b1.y;
        Bs[lc4 + 2][lr + 64] = b1.z; Bs[lc4 + 3][lr + 64] = b1.w;
        __syncthreads();

        #pragma unroll
        for (int k = 0; k < TK; k++) {
            const float4 a0v = *(const float4*)&As[k][ty * 4];
            const float4 a1v = *(const float4*)&As[k][ty * 4 + 64];
            const float4 b0v = *(const float4*)&Bs[k][tx * 4];
            const float4 b1v = *(const float4*)&Bs[k][tx * 4 + 64];
            const float av[8] = {a0v.x, a0v.y, a0v.z, a0v.w,
                                 a1v.x, a1v.y, a1v.z, a1v.w};
            const float bv[8] = {b0v.x, b0v.y, b0v.z, b0v.w,
                                 b1v.x, b1v.y, b1v.z, b1v.w};
            #pragma unroll
            for (int i = 0; i < 8; i++)
                #pragma unroll
                for (int j = 0; j < 8; j++)
                    acc[i][j] = fmaf(av[i], bv[j], acc[i][j]);
        }
    }

    #pragma unroll
    for (int ih = 0; ih < 2; ih++) {
        #pragma unroll
        for (int ii = 0; ii < 4; ii++) {
            const int i = ih * 4 + ii;
            const int r = m0 + ih * 64 + ty * 4 + ii;
            #pragma unroll
            for (int jh = 0; jh < 2; jh++) {
                const int c0 = n0 + jh * 64 + tx * 4;
                float4 v = make_float4(acc[i][jh * 4 + 0], acc[i][jh * 4 + 1],
                                       acc[i][jh * 4 + 2], acc[i][jh * 4 + 3]);
                if (EPI == 1) {
                    const float4 bi = *(const float4*)(bias + c0);
                    v.x = softplus_f(v.x + bi.x);
                    v.y = softplus_f(v.y + bi.y);
                    v.z = softplus_f(v.z + bi.z);
                    v.w = softplus_f(v.w + bi.w);
                }
                if (!NG || (c0 + 3) < N) {
                    *(float4*)(C + (size_t)r * ldc + c0) = v;
                } else {
                    const float vv[4] = {v.x, v.y, v.z, v.w};
                    #pragma unroll
                    for (int e = 0; e < 4; e++)
                        if (c0 + e < N) C[(size_t)r * ldc + c0 + e] = vv[e];
                }
            }
        }
    }
}

// ---------------------------------------------------------------------------
// Sum 8 split-K partials (proj): out[i] = sum_z pp[z*327680 + i], float4 i
// ---------------------------------------------------------------------------
__global__ __launch_bounds__(256) void reduce8_k(const float* __restrict__ pp,
                                                 float* __restrict__ out) {
    const int i = blockIdx.x * 256 + threadIdx.x;   // float4 index, n4 = 81920
    float4 s = ((const float4*)pp)[i];
    #pragma unroll
    for (int z = 1; z < 8; ++z) {
        const float4 v = ((const float4*)(pp + (size_t)z * 327680))[i];
        s.x += v.x; s.y += v.y; s.z += v.z; s.w += v.w;
    }
    ((float4*)out)[i] = s;
}

// ---------------------------------------------------------------------------
// Depthwise causal conv (k=2) + SiLU
// ---------------------------------------------------------------------------
__global__ __launch_bounds__(256) void conv_k(const float* __restrict__ xz,
                                              const float* __restrict__ w,
                                              const float* __restrict__ cb,
                                              float* __restrict__ xc) {
    const int idx = blockIdx.x * 256 + threadIdx.x;
    const int t = idx >> 8;
    const int d4 = (idx & 255) << 2;
    const int l = t & (LSEQ - 1);

    const float4 cur = *(const float4*)(xz + (size_t)t * 2048 + d4);
    float4 prev = make_float4(0.f, 0.f, 0.f, 0.f);
    if (l > 0) prev = *(const float4*)(xz + (size_t)(t - 1) * 2048 + d4);

    const float4 wa = *(const float4*)(w + d4 * 2);
    const float4 wb = *(const float4*)(w + d4 * 2 + 4);
    const float4 bb = *(const float4*)(cb + d4);

    float4 o;
    o.x = silu_f(prev.x * wa.x + cur.x * wa.y + bb.x);
    o.y = silu_f(prev.y * wa.z + cur.y * wa.w + bb.y);
    o.z = silu_f(prev.z * wb.x + cur.z * wb.y + bb.z);
    o.w = silu_f(prev.w * wb.z + cur.w * wb.w + bb.w);
    *(float4*)(xc + (size_t)t * DM + d4) = o;
}

// ---------------------------------------------------------------------------
// Selective scan, 3-phase chunked.
// P/S/hin layout: [b][d][chunk][n] = ((b*1024+d)*64 + chunk)*8 + n
// ---------------------------------------------------------------------------
__global__ __launch_bounds__(256) void scanA_k(const float* __restrict__ delta,
                                               const float* __restrict__ xc,
                                               const float* __restrict__ proj,
                                               const float* __restrict__ A_log,
                                               float* __restrict__ P,
                                               float* __restrict__ S) {
    const int bx = blockIdx.x;
    const int dblk = bx & 3;
    const int chunk = (bx >> 2) & 63;
    const int b = bx >> 8;
    const int d = dblk * 256 + threadIdx.x;
    const int t0 = b * LSEQ + chunk * LCHUNK;

    __shared__ float sB[LCHUNK][NSTATE];
    {
        const int l = threadIdx.x >> 3, n = threadIdx.x & 7;
        sB[l][n] = proj[(size_t)(t0 + l) * 80 + 64 + n];
    }
    __syncthreads();

    float nA[8], h[8], Pp[8];
    #pragma unroll
    for (int n = 0; n < 8; n++) {
        nA[n] = -expf(A_log[d * 8 + n]);
        h[n] = 0.f;
        Pp[n] = 1.f;
    }
    for (int l = 0; l < LCHUNK; l++) {
        const int t = t0 + l;
        const float dl = delta[(size_t)t * DM + d];
        const float xcv = xc[(size_t)t * DM + d];
        const float dx = dl * xcv;
        #pragma unroll
        for (int n = 0; n < 8; n++) {
            const float dA = expf(dl * nA[n]);
            h[n] = fmaf(dA, h[n], dx * sB[l][n]);
            Pp[n] *= dA;
        }
    }
    const size_t base = ((size_t)(b * DM + d) * NCHUNK + chunk) * NSTATE;
    #pragma unroll
    for (int n = 0; n < 8; n++) {
        P[base + n] = Pp[n];
        S[base + n] = h[n];
    }
}

__global__ __launch_bounds__(256) void scanB_k(const float* __restrict__ P,
                                               const float* __restrict__ S,
                                               float* __restrict__ hin) {
    const int idx = blockIdx.x * 256 + threadIdx.x;
    const int n = idx & 7;
    const int bd = idx >> 3;
    const size_t base = (size_t)bd * NCHUNK * NSTATE + n;
    float h = 0.f;
    for (int c = 0; c < NCHUNK; c++) {
        const size_t a = base + (size_t)c * NSTATE;
        hin[a] = h;
        h = fmaf(P[a], h, S[a]);
    }
}

__global__ __launch_bounds__(256) void scanC_k(const float* __restrict__ delta,
                                               const float* __restrict__ xc,
                                               const float* __restrict__ proj,
                                               const float* __restrict__ A_log,
                                               const float* __restrict__ Dskip,
                                               const float* __restrict__ xz,
                                               const float* __restrict__ hin,
                                               unsigned short* __restrict__ yh,
                                               unsigned short* __restrict__ yl) {
    const int bx = blockIdx.x;
    const int dblk = bx & 3;
    const int chunk = (bx >> 2) & 63;
    const int b = bx >> 8;
    const int d = dblk * 256 + threadIdx.x;
    const int t0 = b * LSEQ + chunk * LCHUNK;

    __shared__ float sB[LCHUNK][NSTATE];
    __shared__ float sC[LCHUNK][NSTATE];
    {
        const int l = threadIdx.x >> 3, n = threadIdx.x & 7;
        sB[l][n] = proj[(size_t)(t0 + l) * 80 + 64 + n];
        sC[l][n] = proj[(size_t)(t0 + l) * 80 + 72 + n];
    }
    __syncthreads();

    const size_t base = ((size_t)(b * DM + d) * NCHUNK + chunk) * NSTATE;
    float nA[8], h[8];
    #pragma unroll
    for (int n = 0; n < 8; n++) {
        nA[n] = -expf(A_log[d * 8 + n]);
        h[n] = hin[base + n];
    }
    const float dsk = Dskip[d];
    for (int l = 0; l < LCHUNK; l++) {
        const int t = t0 + l;
        const float dl = delta[(size_t)t * DM + d];
        const float xcv = xc[(size_t)t * DM + d];
        const float dx = dl * xcv;
        float yv = 0.f;
        #pragma unroll
        for (int n = 0; n < 8; n++) {
            const float dA = expf(dl * nA[n]);
            h[n] = fmaf(dA, h[n], dx * sB[l][n]);
            yv = fmaf(h[n], sC[l][n], yv);
        }
        const float zv = xz[(size_t)t * 2048 + DM + d];
        const float out = (yv + dsk * xcv) * silu_f(zv);
        unsigned short hh, ll;
        split2(out, hh, ll);
        yh[(size_t)t * DM + d] = hh;
        yl[(size_t)t * DM + d] = ll;
    }
}

// ---------------------------------------------------------------------------
// LayerNorm; optional add; optional bf16 hi/lo emission of the final value
// ---------------------------------------------------------------------------
__global__ __launch_bounds__(256) void ln_k(const float* __restrict__ in,
                                            const float* __restrict__ gamma,
                                            const float* __restrict__ beta,
                                            const float* __restrict__ add,
                                            float* __restrict__ out,
                                            unsigned short* __restrict__ oh,
                                            unsigned short* __restrict__ ol,
                                            int hasAdd) {
    const int row = blockIdx.x;
    const int tid = threadIdx.x;
    const float4 v = *(const float4*)(in + (size_t)row * DM + tid * 4);

    float s = v.x + v.y + v.z + v.w;
    #pragma unroll
    for (int o = 32; o; o >>= 1) s += __shfl_down(s, o);
    __shared__ float red[4];
    if ((tid & 63) == 0) red[tid >> 6] = s;
    __syncthreads();
    const float mu = (red[0] + red[1] + red[2] + red[3]) * (1.f / DM);

    float4 dv;
    dv.x = v.x - mu; dv.y = v.y - mu; dv.z = v.z - mu; dv.w = v.w - mu;
    float s2 = dv.x * dv.x + dv.y * dv.y + dv.z * dv.z + dv.w * dv.w;
    #pragma unroll
    for (int o = 32; o; o >>= 1) s2 += __shfl_down(s2, o);
    __syncthreads();
    if ((tid & 63) == 0) red[tid >> 6] = s2;
    __syncthreads();
    const float var = (red[0] + red[1] + red[2] + red[3]) * (1.f / DM);
    const float rs = rsqrtf(var + 1e-5f);

    const float4 g = *(const float4*)(gamma + tid * 4);
    const float4 bt = *(const float4*)(beta + tid * 4);
    float4 o4;
    o4.x = dv.x * rs * g.x + bt.x;
    o4.y = dv.y * rs * g.y + bt.y;
    o4.z = dv.z * rs * g.z + bt.z;
    o4.w = dv.w * rs * g.w + bt.w;
    if (hasAdd) {
        const float4 a = *(const float4*)(add + (size_t)row * DM + tid * 4);
        o4.x += a.x; o4.y += a.y; o4.z += a.z; o4.w += a.w;
    }
    *(float4*)(out + (size_t)row * DM + tid * 4) = o4;
    if (oh) {
        const size_t i0 = (size_t)row * DM + tid * 4;
        ushort4 h, l;
        split2(o4.x, h.x, l.x);
        split2(o4.y, h.y, l.y);
        split2(o4.z, h.z, l.z);
        split2(o4.w, h.w, l.w);
        *(ushort4*)(oh + i0) = h;
        *(ushort4*)(ol + i0) = l;
    }
}

// ---------------------------------------------------------------------------
// Host-side orchestration
// ---------------------------------------------------------------------------
extern "C" void kernel_launch(void* const* d_in, const int* in_sizes, int n_in,
                              void* d_out, int out_size, void* d_ws,
                              size_t ws_size, hipStream_t stream) {
    const float* x = (const float*)d_in[0];
    auto F = [&](int i) { return (const float*)d_in[i]; };

    float* ws = (float*)d_ws;
    float* xt    = ws + 0;            //  4M floats
    float* xz    = ws + 4194304;      //  8M floats
    float* xc    = ws + 12582912;     //  4M
    float* delta = ws + 16777216;     //  4M
    float* proj  = ws + 20971520;     //  0.33M
    unsigned short* y_h = (unsigned short*)(ws + 21299200);  // 4M ushorts
    unsigned short* y_l = (unsigned short*)(ws + 23396352);
    float* Pb    = ws + 25493504;     //  1M
    float* Sb    = ws + 26542080;     //  1M
    float* hin   = ws + 27590656;     //  1M
    float* osum  = ws + 28639232;     //  4M
    float* pp    = osum;              // alias: proj split-K partials (2.62M),
                                      // osum not live until bwd W_out
    unsigned short* xt_h = (unsigned short*)(ws + 32833536);  // 4M ushorts
    unsigned short* xt_l = (unsigned short*)(ws + 34930688);
    unsigned short* o_h  = xt_h;      // alias: xt_h/l dead after bwd W_in GEMM
    unsigned short* o_l  = xt_l;
    unsigned short* w_h  = (unsigned short*)(ws + 37027840);  // <=4M ushorts
    unsigned short* w_l  = (unsigned short*)(ws + 39124992);
    // FFN1 bf16 outputs alias dead regions: f1_h over xz, f1_l over xc+delta
    unsigned short* f1_h = (unsigned short*)(ws + 4194304);
    unsigned short* f1_l = (unsigned short*)(ws + 12582912);

    float* obuf = (float*)d_out;      // alias: fully rewritten by final LN

    const dim3 blk(256);
    const dim3 gIn(2048 / 128, NTOK / 128);      // W_in, BN=128: 512 blocks
    const dim3 gSq64(1024 / 64, NTOK / 128);     // N=1024, BN=64: 512 blocks
    const dim3 gF1(4096 / 128, NTOK / 128);      // FFN1, BN=128: 1024 blocks
    const dim3 gPr(1, NTOK / TM, 8);             // proj split-K: 256 blocks
    const dim3 gDt(8, NTOK / TM);                // delta: 256 blocks

    transpose_k<<<dim3(LSEQ / 32, DM / 32, 2), dim3(32, 8), 0, stream>>>(
        x, xt, xt_h, xt_l);

    // ================= forward direction =================
    {
        split_k<<<2048, blk, 0, stream>>>(F(1), w_h, w_l, 2048 * 1024 / 4);
        gemm3_k<0, 0, 128><<<gIn, blk, 0, stream>>>(
            xt_h, xt_l, w_h, w_l, xz, nullptr, nullptr, 1024, 2048,
            nullptr, nullptr, 0);
        conv_k<<<NTOK, blk, 0, stream>>>(xz, F(2), F(3), xc);
        gemm_k<0, 0, true><<<gPr, blk, 0, stream>>>(
            xc, F(4), pp, NTOK, 80, 1024, 1024, 80, nullptr, nullptr, 0,
            128, 327680);
        reduce8_k<<<320, blk, 0, stream>>>(pp, proj);
        gemm_k<0, 1, false><<<gDt, blk, 0, stream>>>(
            proj, F(5), delta, NTOK, 1024, 64, 80, 1024, F(6), nullptr, 0,
            64, 0);
        scanA_k<<<512, blk, 0, stream>>>(delta, xc, proj, F(7), Pb, Sb);
        scanB_k<<<64, blk, 0, stream>>>(Pb, Sb, hin);
        scanC_k<<<512, blk, 0, stream>>>(delta, xc, proj, F(7), F(8), xz, hin,
                                         y_h, y_l);
        split_k<<<1024, blk, 0, stream>>>(F(9), w_h, w_l, 1024 * 1024 / 4);
        gemm3_k<0, 3, 64><<<gSq64, blk, 0, stream>>>(
            y_h, y_l, w_h, w_l, obuf, nullptr, nullptr, 1024, 1024,
            nullptr, xt, 1024);
        ln_k<<<NTOK, blk, 0, stream>>>(obuf, F(19), F(20), nullptr, obuf,
                                       nullptr, nullptr, 0);
    }
    // ================= backward direction =================
    {
        split_k<<<2048, blk, 0, stream>>>(F(10), w_h, w_l, 2048 * 1024 / 4);
        gemm3_k<1, 0, 128><<<gIn, blk, 0, stream>>>(
            xt_h, xt_l, w_h, w_l, xz, nullptr, nullptr, 1024, 2048,
            nullptr, nullptr, 0);
        conv_k<<<NTOK, blk, 0, stream>>>(xz, F(11), F(12), xc);
        gemm_k<0, 0, true><<<gPr, blk, 0, stream>>>(
            xc, F(13), pp, NTOK, 80, 1024, 1024, 80, nullptr, nullptr, 0,
            128, 327680);
        reduce8_k<<<320, blk, 0, stream>>>(pp, proj);
        gemm_k<0, 1, false><<<gDt, blk, 0, stream>>>(
            proj, F(14), delta, NTOK, 1024, 64, 80, 1024, F(15), nullptr, 0,
            64, 0);
        scanA_k<<<512, blk, 0, stream>>>(delta, xc, proj, F(16), Pb, Sb);
        scanB_k<<<64, blk, 0, stream>>>(Pb, Sb, hin);
        scanC_k<<<512, blk, 0, stream>>>(delta, xc, proj, F(16), F(17), xz, hin,
                                         y_h, y_l);
        split_k<<<1024, blk, 0, stream>>>(F(18), w_h, w_l, 1024 * 1024 / 4);
        // store reversed + add xt at reversed rows -> osum = xt + ob
        gemm3_k<0, 4, 64><<<gSq64, blk, 0, stream>>>(
            y_h, y_l, w_h, w_l, osum, nullptr, nullptr, 1024, 1024,
            nullptr, xt, 1024);
        // o = LN(osum)*g+b + obuf -> obuf (+ bf16 hi/lo for FFN1)
        ln_k<<<NTOK, blk, 0, stream>>>(osum, F(21), F(22), obuf, obuf,
                                       o_h, o_l, 1);
    }
    // ================= FFN + final LN =================
    split_k<<<4096, blk, 0, stream>>>(F(25), w_h, w_l, 4096 * 1024 / 4);
    gemm3_k<0, 1, 128><<<gF1, blk, 0, stream>>>(
        o_h, o_l, w_h, w_l, nullptr, f1_h, f1_l, 1024, 4096,
        F(26), nullptr, 0);
    split_k<<<4096, blk, 0, stream>>>(F(27), w_h, w_l, 1024 * 4096 / 4);
    gemm3_k<0, 2, 64><<<gSq64, blk, 0, stream>>>(
        f1_h, f1_l, w_h, w_l, osum, nullptr, nullptr, 4096, 1024,
        F(28), obuf, 1024);
    ln_k<<<NTOK, blk, 0, stream>>>(osum, F(23), F(24), nullptr, (float*)d_out,
                                   nullptr, nullptr, 0);
}